// Round 1
// baseline (148.976 us; speedup 1.0000x reference)
//
#include <hip/hip_runtime.h>
#include <math.h>

// Problem constants (fixed by setup_inputs)
static constexpr int Cc   = 16;   // C
static constexpr int COc  = 16;   // CO
static constexpr int Hh   = 4;    // heads
static constexpr int CHc  = 4;    // CO/H
static constexpr int CPWc = 32;   // 2*C
static constexpr int NTH  = 256;  // block size

// ---------------------------------------------------------------------------
// Kernel 1: per-row first-layer projections.
//   q rows: aW[r][j] = b1[j] + sum_i xq[i]*(w1[i][j]-w1[i+16][j])   (j<32)
//           aV[r][j] = bv1[j] + sum_i xq[i]*(v1[i][j]-v1[i+16][j])  (j<16)
//   k rows: cW[r][j] =          sum_i xk[i]*w1[i+16][j]
//           cV[r][j] =          sum_i xk[i]*v1[i+16][j]
// ---------------------------------------------------------------------------
__global__ __launch_bounds__(NTH) void ppa_precompute(
    const float* __restrict__ xq, const float* __restrict__ xk,
    const float* __restrict__ w1, const float* __restrict__ b1,
    const float* __restrict__ v1, const float* __restrict__ bv1,
    float* __restrict__ aW, float* __restrict__ aV,
    float* __restrict__ cW, float* __restrict__ cV,
    int BN, int BK) {
  __shared__ float sw1[CPWc * CPWc];  // 1024
  __shared__ float sv1[CPWc * COc];   // 512
  __shared__ float sb1[CPWc];
  __shared__ float sbv1[COc];
  const int t = threadIdx.x;
  for (int i = t; i < CPWc * CPWc; i += NTH) sw1[i] = w1[i];
  for (int i = t; i < CPWc * COc; i += NTH) sv1[i] = v1[i];
  if (t < CPWc) sb1[t] = b1[t];
  if (t < COc) sbv1[t] = bv1[t];
  __syncthreads();

  const int r = blockIdx.x * NTH + t;
  if (r >= BN + BK) return;
  const bool isQ = (r < BN);
  const int rr = isQ ? r : (r - BN);
  const float* src = isQ ? (xq + (size_t)rr * Cc) : (xk + (size_t)rr * Cc);

  float x[Cc];
#pragma unroll
  for (int i = 0; i < Cc; i += 4) {
    float4 v = *reinterpret_cast<const float4*>(src + i);
    x[i] = v.x; x[i + 1] = v.y; x[i + 2] = v.z; x[i + 3] = v.w;
  }

  if (isQ) {
#pragma unroll
    for (int j = 0; j < CPWc; ++j) {
      float acc = sb1[j];
#pragma unroll
      for (int i = 0; i < Cc; ++i)
        acc += x[i] * (sw1[i * CPWc + j] - sw1[(i + Cc) * CPWc + j]);
      aW[(size_t)rr * CPWc + j] = acc;
    }
#pragma unroll
    for (int j = 0; j < COc; ++j) {
      float acc = sbv1[j];
#pragma unroll
      for (int i = 0; i < Cc; ++i)
        acc += x[i] * (sv1[i * COc + j] - sv1[(i + Cc) * COc + j]);
      aV[(size_t)rr * COc + j] = acc;
    }
  } else {
#pragma unroll
    for (int j = 0; j < CPWc; ++j) {
      float acc = 0.f;
#pragma unroll
      for (int i = 0; i < Cc; ++i) acc += x[i] * sw1[(i + Cc) * CPWc + j];
      cW[(size_t)rr * CPWc + j] = acc;
    }
#pragma unroll
    for (int j = 0; j < COc; ++j) {
      float acc = 0.f;
#pragma unroll
      for (int i = 0; i < Cc; ++i) acc += x[i] * sv1[(i + Cc) * COc + j];
      cV[(size_t)rr * COc + j] = acc;
    }
  }
}

// ---------------------------------------------------------------------------
// Kernel 2: one block per (b,n) output row. 256 threads, each handles
// Nk/256 = 4 k-values with an online-softmax accumulator, then a
// wave-butterfly + cross-wave merge.
// ---------------------------------------------------------------------------
__global__ __launch_bounds__(NTH) void ppa_main(
    const float* __restrict__ aW, const float* __restrict__ aV,
    const float* __restrict__ cW, const float* __restrict__ cV,
    const float* __restrict__ w2, const float* __restrict__ b2,
    const float* __restrict__ v2, const float* __restrict__ bv2,
    float* __restrict__ out, int N, int Nk) {
  __shared__ float sw2[CPWc * Hh];   // 128: row j = 4 floats (one head each)
  __shared__ float sb2[Hh];
  __shared__ float sv2[COc * COc];   // 256
  __shared__ float sbv2[COc];
  __shared__ float sa[CPWc];
  __shared__ float sav[COc];
  __shared__ float red[4][8 + COc];  // per-wave m[4], l[4], o[16]

  const int t = threadIdx.x;
  const int row = blockIdx.x;  // [0, B*N)
  const int b = row / N;

  if (t < CPWc * Hh) sw2[t] = w2[t];
  if (t < Hh) sb2[t] = b2[t];
  sv2[t] = v2[t];  // NTH == 256 == COc*COc
  if (t < COc) sbv2[t] = bv2[t];
  if (t < CPWc) sa[t] = aW[(size_t)row * CPWc + t];
  if (t < COc) sav[t] = aV[(size_t)row * COc + t];
  __syncthreads();

  float a[CPWc], av[COc];
#pragma unroll
  for (int j = 0; j < CPWc; ++j) a[j] = sa[j];
#pragma unroll
  for (int j = 0; j < COc; ++j) av[j] = sav[j];

  // logits are ReLU'd => >= 0, so m=0 is a valid initial running max.
  float m[Hh], l[Hh], o[COc];
#pragma unroll
  for (int h = 0; h < Hh; ++h) { m[h] = 0.f; l[h] = 0.f; }
#pragma unroll
  for (int c = 0; c < COc; ++c) o[c] = 0.f;

  const float* cWb = cW + (size_t)b * Nk * CPWc;
  const float* cVb = cV + (size_t)b * Nk * COc;

  for (int kk = 0; kk < Nk; kk += NTH) {
    const int k = kk + t;

    // hw = relu(a + c_k)
    float hw[CPWc];
#pragma unroll
    for (int j = 0; j < CPWc; j += 4) {
      float4 v = *reinterpret_cast<const float4*>(cWb + (size_t)k * CPWc + j);
      hw[j]     = fmaxf(a[j]     + v.x, 0.f);
      hw[j + 1] = fmaxf(a[j + 1] + v.y, 0.f);
      hw[j + 2] = fmaxf(a[j + 2] + v.z, 0.f);
      hw[j + 3] = fmaxf(a[j + 3] + v.w, 0.f);
    }

    // logits = relu(hw @ w2 + b2)
    float lg[Hh];
#pragma unroll
    for (int h = 0; h < Hh; ++h) lg[h] = sb2[h];
#pragma unroll
    for (int j = 0; j < CPWc; ++j) {
      float4 w = *reinterpret_cast<const float4*>(&sw2[j * Hh]);
      lg[0] += hw[j] * w.x;
      lg[1] += hw[j] * w.y;
      lg[2] += hw[j] * w.z;
      lg[3] += hw[j] * w.w;
    }
#pragma unroll
    for (int h = 0; h < Hh; ++h) lg[h] = fmaxf(lg[h], 0.f);

    // hv = relu(av + cv_k)
    float hv[COc];
#pragma unroll
    for (int j = 0; j < COc; j += 4) {
      float4 v = *reinterpret_cast<const float4*>(cVb + (size_t)k * COc + j);
      hv[j]     = fmaxf(av[j]     + v.x, 0.f);
      hv[j + 1] = fmaxf(av[j + 1] + v.y, 0.f);
      hv[j + 2] = fmaxf(av[j + 2] + v.z, 0.f);
      hv[j + 3] = fmaxf(av[j + 3] + v.w, 0.f);
    }

    // value = relu(hv @ v2 + bv2)
    float val[COc];
#pragma unroll
    for (int c = 0; c < COc; ++c) val[c] = sbv2[c];
#pragma unroll
    for (int j = 0; j < COc; ++j) {
      const float hvj = hv[j];
#pragma unroll
      for (int c = 0; c < COc; c += 4) {
        float4 v = *reinterpret_cast<const float4*>(&sv2[j * COc + c]);
        val[c]     += hvj * v.x;
        val[c + 1] += hvj * v.y;
        val[c + 2] += hvj * v.z;
        val[c + 3] += hvj * v.w;
      }
    }
#pragma unroll
    for (int c = 0; c < COc; ++c) val[c] = fmaxf(val[c], 0.f);

    // online softmax update
#pragma unroll
    for (int h = 0; h < Hh; ++h) {
      const float mn = fmaxf(m[h], lg[h]);
      const float s = __expf(m[h] - mn);
      const float p = __expf(lg[h] - mn);
      l[h] = l[h] * s + p;
#pragma unroll
      for (int c = 0; c < CHc; ++c)
        o[h * CHc + c] = o[h * CHc + c] * s + p * val[h * CHc + c];
      m[h] = mn;
    }
  }

  // wave-level butterfly merge (64 lanes)
#pragma unroll
  for (int off = 1; off < 64; off <<= 1) {
    float s0[Hh], s1[Hh];
#pragma unroll
    for (int h = 0; h < Hh; ++h) {
      const float mo = __shfl_xor(m[h], off);
      const float lo = __shfl_xor(l[h], off);
      const float mn = fmaxf(m[h], mo);
      s0[h] = __expf(m[h] - mn);
      s1[h] = __expf(mo - mn);
      l[h] = l[h] * s0[h] + lo * s1[h];
      m[h] = mn;
    }
#pragma unroll
    for (int c = 0; c < COc; ++c) {
      const float oo = __shfl_xor(o[c], off);
      o[c] = o[c] * s0[c >> 2] + oo * s1[c >> 2];
    }
  }

  const int lane = t & 63;
  const int wid = t >> 6;
  if (lane == 0) {
#pragma unroll
    for (int h = 0; h < Hh; ++h) { red[wid][h] = m[h]; red[wid][4 + h] = l[h]; }
#pragma unroll
    for (int c = 0; c < COc; ++c) red[wid][8 + c] = o[c];
  }
  __syncthreads();

  // final 4-way merge: one lane per output channel
  if (t < COc) {
    const int h = t >> 2;
    const float mn = fmaxf(fmaxf(red[0][h], red[1][h]), fmaxf(red[2][h], red[3][h]));
    float lsum = 0.f, osum = 0.f;
#pragma unroll
    for (int w = 0; w < 4; ++w) {
      const float s = __expf(red[w][h] - mn);
      lsum += red[w][4 + h] * s;
      osum += red[w][8 + t] * s;
    }
    out[(size_t)row * COc + t] = osum / lsum;
  }
}

// ---------------------------------------------------------------------------
extern "C" void kernel_launch(void* const* d_in, const int* in_sizes, int n_in,
                              void* d_out, int out_size, void* d_ws, size_t ws_size,
                              hipStream_t stream) {
  const float* xq  = (const float*)d_in[0];
  const float* xk  = (const float*)d_in[1];
  const float* w1  = (const float*)d_in[2];
  const float* b1  = (const float*)d_in[3];
  const float* w2  = (const float*)d_in[4];
  const float* b2  = (const float*)d_in[5];
  const float* v1  = (const float*)d_in[6];
  const float* bv1 = (const float*)d_in[7];
  const float* v2  = (const float*)d_in[8];
  const float* bv2 = (const float*)d_in[9];
  float* out = (float*)d_out;

  const int BN = in_sizes[0] / Cc;  // B*N  = 2048
  const int BK = in_sizes[1] / Cc;  // B*Nk = 2048
  const int B = 2;                  // fixed by setup_inputs
  const int N = BN / B;
  const int Nk = BK / B;

  float* ws = (float*)d_ws;
  float* aW = ws;                          // BN*32
  float* aV = aW + (size_t)BN * CPWc;      // BN*16
  float* cW = aV + (size_t)BN * COc;       // BK*32
  float* cV = cW + (size_t)BK * CPWc;      // BK*16

  const int totalRows = BN + BK;
  const int pgrid = (totalRows + NTH - 1) / NTH;
  ppa_precompute<<<pgrid, NTH, 0, stream>>>(xq, xk, w1, b1, v1, bv1,
                                            aW, aV, cW, cV, BN, BK);
  ppa_main<<<BN, NTH, 0, stream>>>(aW, aV, cW, cV, w2, b2, v2, bv2, out, N, Nk);
}